// Round 1
// baseline (151.700 us; speedup 1.0000x reference)
//
#include <hip/hip_runtime.h>
#include <math.h>

#define B_TOT 8192
#define D_ 64
#define W_ 128
#define H_ 128
#define NCOL 256

// ws float offsets
#define WS_FWM     0        // 384*256 folded main weights
#define WS_FWMEM   98304    // 384*3 folded mem-head weights
#define WS_BIASM   99456    // 256 folded main bias
#define WS_BIASMEM 99712    // 3 folded mem bias

// out float offsets (return order: stack_new, next_state, logits_buf, action_probs)
#define OUT_STACK 0
#define OUT_STATE 67108864UL
#define OUT_BUF   68157440UL
#define OUT_PROBS 69206016UL

#define NB_GEMM 512
#define BROWS 16

__global__ __launch_bounds__(256) void fold_kernel(
    const float* __restrict__ W_state, const float* __restrict__ b_state,
    const float* __restrict__ W_top,   const float* __restrict__ b_top,
    const float* __restrict__ W_mem,   const float* __restrict__ b_mem,
    const float* __restrict__ W_buf,   const float* __restrict__ b_buf,
    const float* __restrict__ W_stateout, const float* __restrict__ b_stateout,
    float* __restrict__ ws)
{
    int k = blockIdx.x;   // 0..383 (row of folded 384x259 weight)
    int j = threadIdx.x;  // 0..255 (col: 0..127 -> buf head, 128..255 -> stateout head)
    int col = j & 127;
    const float* Whead = (j < 128) ? W_buf : W_stateout;
    const float* bhead = (j < 128) ? b_buf : b_stateout;
    float v;
    if (k < 128) {
        v = Whead[k*H_ + col];
    } else if (k < 256) {
        const float* a = W_state + (size_t)(k-128)*H_;
        float s = 0.f;
        for (int t = 0; t < 128; ++t) s += a[t] * Whead[(128+t)*H_ + col];
        v = s;
    } else {
        const float* a = W_top + (size_t)(k-256)*H_;
        float s = 0.f;
        for (int t = 0; t < 128; ++t) s += a[t] * Whead[(256+t)*H_ + col];
        v = s;
    }
    ws[WS_FWM + k*NCOL + j] = v;

    if (j < 3) {  // mem head (3 cols)
        float v2;
        if (k < 128) v2 = W_mem[k*3 + j];
        else if (k < 256) {
            const float* a = W_state + (size_t)(k-128)*H_;
            float s = 0.f;
            for (int t = 0; t < 128; ++t) s += a[t] * W_mem[(128+t)*3 + j];
            v2 = s;
        } else {
            const float* a = W_top + (size_t)(k-256)*H_;
            float s = 0.f;
            for (int t = 0; t < 128; ++t) s += a[t] * W_mem[(256+t)*3 + j];
            v2 = s;
        }
        ws[WS_FWMEM + k*3 + j] = v2;
    }
    if (k == 0) {  // folded biases
        float s = bhead[col];
        for (int t = 0; t < 128; ++t)
            s += b_state[t]*Whead[(128+t)*H_ + col] + b_top[t]*Whead[(256+t)*H_ + col];
        ws[WS_BIASM + j] = s;
        if (j < 3) {
            float s2 = b_mem[j];
            for (int t = 0; t < 128; ++t)
                s2 += b_state[t]*W_mem[(128+t)*3 + j] + b_top[t]*W_mem[(256+t)*3 + j];
            ws[WS_BIASMEM + j] = s2;
        }
    }
}

__global__ __launch_bounds__(256) void main_kernel(
    const float* __restrict__ stack, const float* __restrict__ state_prev,
    const float* __restrict__ x_emb, const float* __restrict__ ws,
    float* __restrict__ out)
{
    int tid = threadIdx.x;
    if (blockIdx.x < NB_GEMM) {
        // ---- GEMM role: 16 rows x 256 cols, K=384 over [x_emb|state_prev|stack_top]
        int b0 = blockIdx.x * BROWS;
        int j = tid;
        const float* __restrict__ FW = ws + WS_FWM;
        float acc[BROWS];
        float bj = ws[WS_BIASM + j];
        #pragma unroll
        for (int r = 0; r < BROWS; ++r) acc[r] = bj;

        const float* src0 = x_emb      + (size_t)b0 * H_;
        const float* src1 = state_prev + (size_t)b0 * H_;
        const float* src2 = stack      + (size_t)b0 * (D_*W_);  // row 0 of each stack = stack_top

        #define SEG(SRC, STRIDE, OFF)                                        \
        for (int k4 = 0; k4 < 32; ++k4) {                                    \
            float w0 = FW[(size_t)((OFF) + k4*4 + 0)*NCOL + j];              \
            float w1 = FW[(size_t)((OFF) + k4*4 + 1)*NCOL + j];              \
            float w2 = FW[(size_t)((OFF) + k4*4 + 2)*NCOL + j];              \
            float w3 = FW[(size_t)((OFF) + k4*4 + 3)*NCOL + j];              \
            _Pragma("unroll")                                                \
            for (int r = 0; r < BROWS; ++r) {                                \
                const float* s = (SRC) + (size_t)r*(STRIDE) + k4*4;          \
                acc[r] += s[0]*w0 + s[1]*w1 + s[2]*w2 + s[3]*w3;             \
            }                                                                \
        }
        SEG(src0, H_, 0)
        SEG(src1, H_, 128)
        SEG(src2, D_*W_, 256)
        #undef SEG

        if (j < 128) {
            #pragma unroll
            for (int r = 0; r < BROWS; ++r)
                out[OUT_BUF + (size_t)(b0+r)*H_ + j] = acc[r];
        } else {
            int c = j - 128;
            #pragma unroll
            for (int r = 0; r < BROWS; ++r)
                out[OUT_STATE + (size_t)(b0+r)*H_ + c] = tanhf(acc[r]);
        }
    } else {
        // ---- Stack role: one block per batch row b
        int b = blockIdx.x - NB_GEMM;
        __shared__ float red[3*256];
        __shared__ float psh[3];
        const float* FM = ws + WS_FWMEM;
        float a0, a1, a2;
        {
            int k = tid;
            float v = (k < 128) ? x_emb[(size_t)b*H_ + k]
                                : state_prev[(size_t)b*H_ + (k-128)];
            a0 = v * FM[k*3+0]; a1 = v * FM[k*3+1]; a2 = v * FM[k*3+2];
            if (k < 128) {
                float v2 = stack[(size_t)b*(D_*W_) + k];  // stack_top
                a0 += v2 * FM[(256+k)*3+0];
                a1 += v2 * FM[(256+k)*3+1];
                a2 += v2 * FM[(256+k)*3+2];
            }
        }
        red[tid] = a0; red[256+tid] = a1; red[512+tid] = a2;
        __syncthreads();
        for (int s = 128; s > 0; s >>= 1) {
            if (tid < s) {
                red[tid]     += red[tid+s];
                red[256+tid] += red[256+tid+s];
                red[512+tid] += red[512+tid+s];
            }
            __syncthreads();
        }
        if (tid == 0) {
            float l0 = red[0]   + ws[WS_BIASMEM+0];
            float l1 = red[256] + ws[WS_BIASMEM+1];
            float l2 = red[512] + ws[WS_BIASMEM+2];
            float m = fmaxf(l0, fmaxf(l1, l2));
            float e0 = __expf(l0-m), e1 = __expf(l1-m), e2 = __expf(l2-m);
            float inv = 1.f / (e0+e1+e2);
            psh[0] = e0*inv; psh[1] = e1*inv; psh[2] = e2*inv;
            out[OUT_PROBS + (size_t)b*3 + 0] = psh[0];
            out[OUT_PROBS + (size_t)b*3 + 1] = psh[1];
            out[OUT_PROBS + (size_t)b*3 + 2] = psh[2];
        }
        __syncthreads();
        float p0 = psh[0], p1 = psh[1], p2 = psh[2];

        // 3-point stencil over depth with rolling float4 registers.
        int w4 = tid & 31;   // float4 index within width-128 row
        int dg = tid >> 5;   // 8 depth-groups of 8
        const float4* sp = (const float4*)(stack + (size_t)b*(D_*W_)) + w4;
        float4*       op = (float4*)(out + OUT_STACK + (size_t)b*(D_*W_)) + w4;
        int d0 = dg * 8;
        float4 cur  = sp[(size_t)d0*32];
        float4 prev = (d0 == 0) ? cur : sp[(size_t)(d0-1)*32];
        #pragma unroll
        for (int i = 0; i < 8; ++i) {
            int d = d0 + i;
            float4 nxt;
            if (d < 63) nxt = sp[(size_t)(d+1)*32];
            else        nxt = make_float4(0.f, 0.f, 0.f, 0.f);
            float4 o;
            o.x = p0*prev.x + p1*nxt.x + p2*cur.x;
            o.y = p0*prev.y + p1*nxt.y + p2*cur.y;
            o.z = p0*prev.z + p1*nxt.z + p2*cur.z;
            o.w = p0*prev.w + p1*nxt.w + p2*cur.w;
            op[(size_t)d*32] = o;
            prev = cur; cur = nxt;
        }
    }
}

extern "C" void kernel_launch(void* const* d_in, const int* in_sizes, int n_in,
                              void* d_out, int out_size, void* d_ws, size_t ws_size,
                              hipStream_t stream) {
    const float* stack      = (const float*)d_in[0];
    const float* state_prev = (const float*)d_in[1];
    const float* x_emb      = (const float*)d_in[2];
    const float* W_state    = (const float*)d_in[3];
    const float* b_state    = (const float*)d_in[4];
    const float* W_top      = (const float*)d_in[5];
    const float* b_top      = (const float*)d_in[6];
    const float* W_mem      = (const float*)d_in[7];
    const float* b_mem      = (const float*)d_in[8];
    const float* W_buf      = (const float*)d_in[9];
    const float* b_buf      = (const float*)d_in[10];
    const float* W_stateout = (const float*)d_in[11];
    const float* b_stateout = (const float*)d_in[12];
    float* out = (float*)d_out;
    float* ws  = (float*)d_ws;

    hipLaunchKernelGGL(fold_kernel, dim3(384), dim3(256), 0, stream,
        W_state, b_state, W_top, b_top, W_mem, b_mem,
        W_buf, b_buf, W_stateout, b_stateout, ws);
    hipLaunchKernelGGL(main_kernel, dim3(NB_GEMM + B_TOT), dim3(256), 0, stream,
        stack, state_prev, x_emb, ws, out);
}